// Round 5
// baseline (443.453 us; speedup 1.0000x reference)
//
#include <hip/hip_runtime.h>

#define VQ_D 64
#define VQ_MARGIN 0.125f

typedef __attribute__((ext_vector_type(8))) short bf16x8;   // 8 bf16 = 4 VGPRs
typedef __attribute__((ext_vector_type(4))) float f32x4;

static __device__ __forceinline__ unsigned short bf16_rne(float v) {
    unsigned u = __float_as_uint(v);
    u += 0x7fffu + ((u >> 16) & 1u);
    return (unsigned short)(u >> 16);
}

// ================= Prep: W -> (Whi, Wlo) bf16 split, wsq (exact fp32), ctr=0 ====
__global__ __launch_bounds__(256) void vq_prep_kernel(
    const float* __restrict__ W, unsigned short* __restrict__ Whi,
    unsigned short* __restrict__ Wlo, float* __restrict__ wsq,
    unsigned int* __restrict__ ctr, int K)
{
    int c = blockIdx.x * 256 + threadIdx.x;
    if (c == 0) *ctr = 0u;
    if (c >= K) return;
    const float4* wr = reinterpret_cast<const float4*>(W) + (size_t)c * (VQ_D / 4);
    unsigned short* hr = Whi + (size_t)c * VQ_D;
    unsigned short* lr = Wlo + (size_t)c * VQ_D;
    float s0 = 0.f, s1 = 0.f, s2 = 0.f, s3 = 0.f;
    #pragma unroll
    for (int j = 0; j < VQ_D / 4; ++j) {
        float4 v = wr[j];
        // wsq with the EXACT round-2/4 structure (recheck kernel depends on it)
        s0 = __fmaf_rn(v.x, v.x, s0); s1 = __fmaf_rn(v.y, v.y, s1);
        s2 = __fmaf_rn(v.z, v.z, s2); s3 = __fmaf_rn(v.w, v.w, s3);
        float vv[4] = {v.x, v.y, v.z, v.w};
        ushort4 h4, l4;
        unsigned short* hp = &h4.x; unsigned short* lp = &l4.x;
        #pragma unroll
        for (int e = 0; e < 4; ++e) {
            unsigned short hb = bf16_rne(vv[e]);
            float hf = __uint_as_float((unsigned)hb << 16);
            hp[e] = hb;
            lp[e] = bf16_rne(vv[e] - hf);
        }
        *reinterpret_cast<ushort4*>(hr + 4 * j) = h4;
        *reinterpret_cast<ushort4*>(lr + 4 * j) = l4;
    }
    wsq[c] = (s0 + s1) + (s2 + s3);
}

// ================= Pass A: MFMA argmin (approx) + top-2 margin flagging =========
// 1 wave / block, 64 rows / wave, full K sweep. A-side = x rows (hi,lo in regs),
// B-side = codes. C layout (m89-verified): col=lane&15 (code), row=(lane>>4)*4+reg.
__global__ __launch_bounds__(64) void vq_mfma_kernel(
    const float* __restrict__ x, const unsigned short* __restrict__ Whi,
    const unsigned short* __restrict__ Wlo, const float* __restrict__ wsq,
    int* __restrict__ idx_final, int* __restrict__ flags,
    unsigned int* __restrict__ ctr, int N, int K)
{
    const int lane = threadIdx.x;     // 0..63
    const int g    = lane >> 4;       // k-group 0..3
    const int c16  = lane & 15;
    const int rbase = blockIdx.x * 64;

    // ---- load 64 rows of x; split to bf16 hi/lo A-fragments in registers ----
    // frag (s,h): rows rbase+s*16+(l&15), k = h*32 + g*8 + j
    bf16x8 xh[4][2], xl[4][2];
    #pragma unroll
    for (int s = 0; s < 4; ++s) {
        int row = rbase + s * 16 + c16;
        if (row >= N) row = N - 1;
        const float* xr = x + (size_t)row * VQ_D;
        #pragma unroll
        for (int h = 0; h < 2; ++h) {
            const float4* p = reinterpret_cast<const float4*>(xr + h * 32 + g * 8);
            float4 v0 = p[0], v1 = p[1];
            float vv[8] = {v0.x, v0.y, v0.z, v0.w, v1.x, v1.y, v1.z, v1.w};
            #pragma unroll
            for (int j = 0; j < 8; ++j) {
                unsigned short hb = bf16_rne(vv[j]);
                float hf = __uint_as_float((unsigned)hb << 16);
                xh[s][h][j] = (short)hb;
                xl[s][h][j] = (short)bf16_rne(vv[j] - hf);
            }
        }
    }

    float d1[4][4], d2[4][4]; int i1[4][4];
    #pragma unroll
    for (int s = 0; s < 4; ++s)
        #pragma unroll
        for (int i = 0; i < 4; ++i) { d1[s][i] = 3.4e38f; d2[s][i] = 3.4e38f; i1[s][i] = 0; }

    const int NT = K >> 4;            // 64 code-tiles of 16
    #pragma unroll 2
    for (int ct = 0; ct < NT; ++ct) {
        const int c = ct * 16 + c16;  // this lane's code column
        const unsigned short* wh = Whi + (size_t)c * VQ_D + g * 8;
        const unsigned short* wl = Wlo + (size_t)c * VQ_D + g * 8;
        bf16x8 bh0 = *reinterpret_cast<const bf16x8*>(wh);
        bf16x8 bh1 = *reinterpret_cast<const bf16x8*>(wh + 32);
        bf16x8 bl0 = *reinterpret_cast<const bf16x8*>(wl);
        bf16x8 bl1 = *reinterpret_cast<const bf16x8*>(wl + 32);
        const float wq = wsq[c];

        #pragma unroll
        for (int s = 0; s < 4; ++s) {
            f32x4 acc = {0.f, 0.f, 0.f, 0.f};
            acc = __builtin_amdgcn_mfma_f32_16x16x32_bf16(xh[s][0], bh0, acc, 0, 0, 0);
            acc = __builtin_amdgcn_mfma_f32_16x16x32_bf16(xh[s][1], bh1, acc, 0, 0, 0);
            acc = __builtin_amdgcn_mfma_f32_16x16x32_bf16(xl[s][0], bh0, acc, 0, 0, 0);
            acc = __builtin_amdgcn_mfma_f32_16x16x32_bf16(xl[s][1], bh1, acc, 0, 0, 0);
            acc = __builtin_amdgcn_mfma_f32_16x16x32_bf16(xh[s][0], bl0, acc, 0, 0, 0);
            acc = __builtin_amdgcn_mfma_f32_16x16x32_bf16(xh[s][1], bl1, acc, 0, 0, 0);
            #pragma unroll
            for (int i = 0; i < 4; ++i) {
                float d = __fmaf_rn(-2.0f, acc[i], wq);      // fsq cancels in argmin
                float o1 = d1[s][i];
                d2[s][i] = fminf(d2[s][i], fmaxf(d, o1));    // streaming 2nd-min (med3 pattern)
                bool lt = d < o1;
                d1[s][i] = lt ? d : o1;
                i1[s][i] = lt ? c : i1[s][i];
            }
        }
    }

    // ---- per-row merge across the 16 code-lanes of each group; write + flag ----
    #pragma unroll
    for (int s = 0; s < 4; ++s)
        #pragma unroll
        for (int i = 0; i < 4; ++i) {
            float a1 = d1[s][i], a2 = d2[s][i]; int ai = i1[s][i];
            #pragma unroll
            for (int m = 1; m < 16; m <<= 1) {   // xor<16 stays inside 16-lane group
                float o1 = __shfl_xor(a1, m, 64);
                float o2 = __shfl_xor(a2, m, 64);
                int   oi = __shfl_xor(ai, m, 64);
                float n1 = fminf(a1, o1);
                a2 = fminf(fminf(a2, o2), fmaxf(a1, o1));
                ai = (o1 < a1) ? oi : ai;
                a1 = n1;
            }
            if (c16 == 0) {
                int row = rbase + s * 16 + g * 4 + i;
                if (row < N) {
                    idx_final[row] = ai;
                    if (a2 - a1 <= VQ_MARGIN) {   // near-tie: exact recheck will decide
                        unsigned int pos = atomicAdd(ctr, 1u);
                        if (pos < (unsigned)N) flags[pos] = row;
                    }
                }
            }
        }
}

// ================= Pass B: exact fp32 recheck of flagged rows ===================
// One wave per flagged row; formula is bit-identical to the proven round-2/4 path.
__global__ __launch_bounds__(256) void vq_recheck_kernel(
    const float* __restrict__ x, const float* __restrict__ W,
    const float* __restrict__ wsq, const int* __restrict__ flags,
    const unsigned int* __restrict__ ctr, int* __restrict__ idx_final, int N, int K)
{
    const int lane = threadIdx.x & 63;
    const int wid  = (blockIdx.x * blockDim.x + threadIdx.x) >> 6;
    const int nw   = (gridDim.x * blockDim.x) >> 6;
    unsigned int cnt = *ctr;
    if (cnt > (unsigned)N) cnt = (unsigned)N;

    const float4* W4 = reinterpret_cast<const float4*>(W);
    for (unsigned int t = wid; t < cnt; t += nw) {
        const int row = flags[t];
        float f[VQ_D];
        {
            const float4* xf = reinterpret_cast<const float4*>(x) + (size_t)row * (VQ_D / 4);
            #pragma unroll
            for (int i = 0; i < VQ_D / 4; ++i) {   // uniform-address broadcast loads
                float4 v = xf[i];
                f[4 * i + 0] = v.x; f[4 * i + 1] = v.y;
                f[4 * i + 2] = v.z; f[4 * i + 3] = v.w;
            }
        }
        float s0 = 0.f, s1 = 0.f, s2 = 0.f, s3 = 0.f;
        #pragma unroll
        for (int q = 0; q < VQ_D; q += 4) {
            s0 = __fmaf_rn(f[q], f[q], s0);         s1 = __fmaf_rn(f[q + 1], f[q + 1], s1);
            s2 = __fmaf_rn(f[q + 2], f[q + 2], s2); s3 = __fmaf_rn(f[q + 3], f[q + 3], s3);
        }
        const float fsq = (s0 + s1) + (s2 + s3);

        float best = 3.4e38f; int bidx = 0x7fffffff;
        for (int tt = 0; tt < K / 64; ++tt) {       // lane scans c = lane + 64*tt (ascending)
            const int c = tt * 64 + lane;
            const float4* wc = W4 + (size_t)c * (VQ_D / 4);
            float d0 = 0.f, dd1 = 0.f, dd2 = 0.f, dd3 = 0.f;
            #pragma unroll
            for (int i = 0; i < VQ_D / 4; ++i) {
                float4 w = wc[i];
                d0  = __fmaf_rn(f[4 * i + 0], w.x, d0);
                dd1 = __fmaf_rn(f[4 * i + 1], w.y, dd1);
                dd2 = __fmaf_rn(f[4 * i + 2], w.z, dd2);
                dd3 = __fmaf_rn(f[4 * i + 3], w.w, dd3);
            }
            float dot  = (d0 + dd1) + (dd2 + dd3);
            float dist = __fmaf_rn(-2.0f, dot, fsq + wsq[c]);
            if (dist < best) { best = dist; bidx = c; }      // strict <: first-index
        }
        #pragma unroll
        for (int m = 1; m < 64; m <<= 1) {          // lexicographic (dist, idx) min
            float od = __shfl_xor(best, m, 64);
            int   oi = __shfl_xor(bidx, m, 64);
            if (od < best || (od == best && oi < bidx)) { best = od; bidx = oi; }
        }
        if (lane == 0) idx_final[row] = bidx;
    }
}

// ================= Pass C: gather + outputs (round-4 proven epilogue) ===========
__global__ __launch_bounds__(256) void vq_gather_kernel(
    const float* __restrict__ x, const float* __restrict__ W,
    const int* __restrict__ idx_final, float* __restrict__ out, int N)
{
    __shared__ int sIdx[64];
    const int tid = threadIdx.x;
    const int rbase = blockIdx.x * 64;
    if (tid < 64 && rbase + tid < N) {
        int idx = idx_final[rbase + tid];
        sIdx[tid] = idx;
        out[(size_t)2 * N * VQ_D + rbase + tid] = (float)idx;   // coalesced
    }
    __syncthreads();
    const float4* W4 = reinterpret_cast<const float4*>(W);
    const float4* X4 = reinterpret_cast<const float4*>(x);
    float4* O0 = reinterpret_cast<float4*>(out);
    float4* O1 = O0 + (size_t)N * (VQ_D / 4);
    const size_t base4 = (size_t)rbase * (VQ_D / 4);
    #pragma unroll
    for (int i = 0; i < 4; ++i) {
        int j = i * 256 + tid;               // 0..1023, lane-consecutive
        int rowo = j >> 4;                   // 16 lanes share a row
        int d4 = j & 15;
        if (rbase + rowo < N) {
            int idx = sIdx[rowo];
            float4 w = W4[(size_t)idx * (VQ_D / 4) + d4];   // 256B contiguous, L2-hot
            float4 xv = X4[base4 + j];
            float4 o;                         // out0 = x + (q - x): ref double-rounding
            o.x = xv.x + (w.x - xv.x);
            o.y = xv.y + (w.y - xv.y);
            o.z = xv.z + (w.z - xv.z);
            o.w = xv.w + (w.w - xv.w);
            O0[base4 + j] = o;
            O1[base4 + j] = w;
        }
    }
}

// ================= Fallback: proven round-4 pipeline ===========================
__global__ __launch_bounds__(256) void vq_wsq_kernel(const float* __restrict__ W,
                                                     float* __restrict__ wsq, int K)
{
    int c = blockIdx.x * 256 + threadIdx.x;
    if (c >= K) return;
    const float4* w4 = reinterpret_cast<const float4*>(W) + (size_t)c * (VQ_D / 4);
    float s0 = 0.f, s1 = 0.f, s2 = 0.f, s3 = 0.f;
    #pragma unroll
    for (int j = 0; j < VQ_D / 4; ++j) {
        float4 v = w4[j];
        s0 = __fmaf_rn(v.x, v.x, s0); s1 = __fmaf_rn(v.y, v.y, s1);
        s2 = __fmaf_rn(v.z, v.z, s2); s3 = __fmaf_rn(v.w, v.w, s3);
    }
    wsq[c] = (s0 + s1) + (s2 + s3);
}

__global__ __launch_bounds__(256, 6) void vq_main_kernel(const float* __restrict__ x,
    const float* __restrict__ W, const float* __restrict__ wsq,
    float* __restrict__ out, int N, int K)
{
    __shared__ unsigned long long sMerge[256];
    __shared__ int sIdx[64];
    const int tid  = threadIdx.x;
    const int lane = tid & 63;
    const int rbase = blockIdx.x * 64;
    const int row  = rbase + lane;
    const int lrow = (row < N) ? row : (N - 1);
    float f[VQ_D];
    {
        const float4* xf = reinterpret_cast<const float4*>(x) + (size_t)lrow * (VQ_D / 4);
        #pragma unroll
        for (int i = 0; i < VQ_D / 4; ++i) {
            float4 v = xf[i];
            f[4 * i + 0] = v.x; f[4 * i + 1] = v.y;
            f[4 * i + 2] = v.z; f[4 * i + 3] = v.w;
        }
    }
    float fsq;
    {
        float s0 = 0.f, s1 = 0.f, s2 = 0.f, s3 = 0.f;
        #pragma unroll
        for (int q = 0; q < VQ_D; q += 4) {
            s0 = __fmaf_rn(f[q], f[q], s0);         s1 = __fmaf_rn(f[q + 1], f[q + 1], s1);
            s2 = __fmaf_rn(f[q + 2], f[q + 2], s2); s3 = __fmaf_rn(f[q + 3], f[q + 3], s3);
        }
        fsq = (s0 + s1) + (s2 + s3);
    }
    const int slice = __builtin_amdgcn_readfirstlane(tid >> 6);
    const int c0 = slice * (K >> 2);
    const int c1 = c0 + (K >> 2);
    float best = 3.4e38f;
    int bidx = c0;
    const float4* __restrict__ W4 = reinterpret_cast<const float4*>(W);
    #pragma unroll 2
    for (int c = c0; c < c1; ++c) {
        const float4* wc = W4 + (size_t)c * (VQ_D / 4);
        float d0 = 0.f, d1 = 0.f, d2 = 0.f, d3 = 0.f;
        #pragma unroll
        for (int i = 0; i < VQ_D / 4; ++i) {
            float4 w = wc[i];
            d0 = __fmaf_rn(f[4 * i + 0], w.x, d0); d1 = __fmaf_rn(f[4 * i + 1], w.y, d1);
            d2 = __fmaf_rn(f[4 * i + 2], w.z, d2); d3 = __fmaf_rn(f[4 * i + 3], w.w, d3);
        }
        float dot = (d0 + d1) + (d2 + d3);
        float dist = __fmaf_rn(-2.0f, dot, fsq + wsq[c]);
        if (dist < best) { best = dist; bidx = c; }
    }
    best = fmaxf(best, 0.0f);
    sMerge[tid] = ((unsigned long long)__float_as_uint(best) << 32) | (unsigned int)bidx;
    __syncthreads();
    if (tid < 64) {
        unsigned long long mm = sMerge[tid];
        unsigned long long a = sMerge[tid + 64];  if (a < mm) mm = a;
        unsigned long long b = sMerge[tid + 128]; if (b < mm) mm = b;
        unsigned long long d = sMerge[tid + 192]; if (d < mm) mm = d;
        int idx = (int)(mm & 0xFFFFFFFFu);
        sIdx[tid] = idx;
        if (rbase + tid < N) out[(size_t)2 * N * VQ_D + rbase + tid] = (float)idx;
    }
    __syncthreads();
    const float4* X4 = reinterpret_cast<const float4*>(x);
    float4* O0 = reinterpret_cast<float4*>(out);
    float4* O1 = O0 + (size_t)N * (VQ_D / 4);
    const size_t base4 = (size_t)rbase * (VQ_D / 4);
    #pragma unroll
    for (int i = 0; i < 4; ++i) {
        int j = i * 256 + tid;
        int rowo = j >> 4, d4 = j & 15;
        if (rbase + rowo < N) {
            int idx = sIdx[rowo];
            float4 w = W4[(size_t)idx * (VQ_D / 4) + d4];
            float4 xv = X4[base4 + j];
            float4 o;
            o.x = xv.x + (w.x - xv.x); o.y = xv.y + (w.y - xv.y);
            o.z = xv.z + (w.z - xv.z); o.w = xv.w + (w.w - xv.w);
            O0[base4 + j] = o; O1[base4 + j] = w;
        }
    }
}

// ================= Launcher ====================================================
extern "C" void kernel_launch(void* const* d_in, const int* in_sizes, int n_in,
                              void* d_out, int out_size, void* d_ws, size_t ws_size,
                              hipStream_t stream)
{
    const float* x = (const float*)d_in[0];
    const float* W = (const float*)d_in[1];
    float* out = (float*)d_out;
    const int N = in_sizes[0] / VQ_D;   // 131072
    const int K = in_sizes[1] / VQ_D;   // 1024

    // ws layout
    char* ws = (char*)d_ws;
    float*          wsq  = (float*)ws;                            // 4 KB
    unsigned int*   ctr  = (unsigned int*)(ws + 4096);            // 4 B (+pad)
    int*            flags= (int*)(ws + 8192);                     // 4N
    int*            idxf = (int*)(ws + 8192 + (size_t)N * 4);     // 4N
    unsigned short* Whi  = (unsigned short*)(ws + 8192 + (size_t)N * 8);
    unsigned short* Wlo  = Whi + (size_t)K * VQ_D;
    const size_t need = 8192 + (size_t)N * 8 + (size_t)K * VQ_D * 4;

    if (ws_size >= need && (N % 64) == 0 && (K % 64) == 0) {
        vq_prep_kernel<<<(K + 255) / 256, 256, 0, stream>>>(W, Whi, Wlo, wsq, ctr, K);
        vq_mfma_kernel<<<(N + 63) / 64, 64, 0, stream>>>(x, Whi, Wlo, wsq,
                                                         idxf, flags, ctr, N, K);
        vq_recheck_kernel<<<128, 256, 0, stream>>>(x, W, wsq, flags, ctr, idxf, N, K);
        vq_gather_kernel<<<(N + 63) / 64, 256, 0, stream>>>(x, W, idxf, out, N);
    } else {
        vq_wsq_kernel<<<(K + 255) / 256, 256, 0, stream>>>(W, wsq, K);
        vq_main_kernel<<<(N + 63) / 64, 256, 0, stream>>>(x, W, wsq, out, N, K);
    }
}

// Round 6
// 206.368 us; speedup vs baseline: 2.1488x; 2.1488x over previous
//
#include <hip/hip_runtime.h>

#define VQ_D 64
#define VQ_MARGIN 0.015f

typedef __attribute__((ext_vector_type(8))) short bf16x8;   // 8 bf16 = 4 VGPRs
typedef __attribute__((ext_vector_type(4))) float f32x4;

static __device__ __forceinline__ unsigned short bf16_rne(float v) {
    unsigned u = __float_as_uint(v);
    u += 0x7fffu + ((u >> 16) & 1u);
    return (unsigned short)(u >> 16);
}

// ================= Prep: W -> (Whi, Wlo) bf16 split, wsq (exact fp32), ctr=0 ====
__global__ __launch_bounds__(256) void vq_prep_kernel(
    const float* __restrict__ W, unsigned short* __restrict__ Whi,
    unsigned short* __restrict__ Wlo, float* __restrict__ wsq,
    unsigned int* __restrict__ ctr, int K)
{
    int c = blockIdx.x * 256 + threadIdx.x;
    if (c == 0) *ctr = 0u;
    if (c >= K) return;
    const float4* wr = reinterpret_cast<const float4*>(W) + (size_t)c * (VQ_D / 4);
    unsigned short* hr = Whi + (size_t)c * VQ_D;
    unsigned short* lr = Wlo + (size_t)c * VQ_D;
    float s0 = 0.f, s1 = 0.f, s2 = 0.f, s3 = 0.f;
    #pragma unroll
    for (int j = 0; j < VQ_D / 4; ++j) {
        float4 v = wr[j];
        // wsq with the EXACT round-2/4 structure (recheck kernel depends on it)
        s0 = __fmaf_rn(v.x, v.x, s0); s1 = __fmaf_rn(v.y, v.y, s1);
        s2 = __fmaf_rn(v.z, v.z, s2); s3 = __fmaf_rn(v.w, v.w, s3);
        float vv[4] = {v.x, v.y, v.z, v.w};
        ushort4 h4, l4;
        unsigned short* hp = &h4.x; unsigned short* lp = &l4.x;
        #pragma unroll
        for (int e = 0; e < 4; ++e) {
            unsigned short hb = bf16_rne(vv[e]);
            float hf = __uint_as_float((unsigned)hb << 16);
            hp[e] = hb;
            lp[e] = bf16_rne(vv[e] - hf);
        }
        *reinterpret_cast<ushort4*>(hr + 4 * j) = h4;
        *reinterpret_cast<ushort4*>(lr + 4 * j) = l4;
    }
    wsq[c] = (s0 + s1) + (s2 + s3);
}

// ================= Pass A: MFMA argmin (approx) + top-2 margin flagging =========
// Block = 256 threads = 4 waves; block owns 64 rows; wave w scans code-tiles
// [w*16, (w+1)*16) (256 codes). Grid = N/64 = 2048 blocks -> 8192 waves.
// Per-wave top-2 merged across 16 code-lanes in-register, then across the 4
// waves via LDS. Any tie (gap 0) or near-tie (gap <= margin) gets flagged for
// the exact recheck, so approximate tie-break order is irrelevant.
__global__ __launch_bounds__(256) void vq_mfma_kernel(
    const float* __restrict__ x, const unsigned short* __restrict__ Whi,
    const unsigned short* __restrict__ Wlo, const float* __restrict__ wsq,
    int* __restrict__ idx_final, int* __restrict__ flags,
    unsigned int* __restrict__ ctr, int N, int K)
{
    __shared__ float sD1[4][64], sD2[4][64];
    __shared__ int   sI1[4][64];

    const int tid  = threadIdx.x;
    const int wv   = tid >> 6;        // wave 0..3
    const int lane = tid & 63;
    const int g    = lane >> 4;       // k-group 0..3
    const int c16  = lane & 15;
    const int rbase = blockIdx.x * 64;

    // ---- load 64 rows of x; split to bf16 hi/lo A-fragments (r5-verified) ----
    bf16x8 xh[4][2], xl[4][2];
    #pragma unroll
    for (int s = 0; s < 4; ++s) {
        int row = rbase + s * 16 + c16;
        if (row >= N) row = N - 1;
        const float* xr = x + (size_t)row * VQ_D;
        #pragma unroll
        for (int h = 0; h < 2; ++h) {
            const float4* p = reinterpret_cast<const float4*>(xr + h * 32 + g * 8);
            float4 v0 = p[0], v1 = p[1];
            float vv[8] = {v0.x, v0.y, v0.z, v0.w, v1.x, v1.y, v1.z, v1.w};
            #pragma unroll
            for (int j = 0; j < 8; ++j) {
                unsigned short hb = bf16_rne(vv[j]);
                float hf = __uint_as_float((unsigned)hb << 16);
                xh[s][h][j] = (short)hb;
                xl[s][h][j] = (short)bf16_rne(vv[j] - hf);
            }
        }
    }

    float d1[4][4], d2[4][4]; int i1[4][4];
    #pragma unroll
    for (int s = 0; s < 4; ++s)
        #pragma unroll
        for (int i = 0; i < 4; ++i) { d1[s][i] = 3.4e38f; d2[s][i] = 3.4e38f; i1[s][i] = 0; }

    const int t0 = wv * (K >> 6);     // 16 tiles per wave
    const int t1 = t0 + (K >> 6);
    #pragma unroll 2
    for (int ct = t0; ct < t1; ++ct) {
        const int c = ct * 16 + c16;  // this lane's code column (global id)
        const unsigned short* wh = Whi + (size_t)c * VQ_D + g * 8;
        const unsigned short* wl = Wlo + (size_t)c * VQ_D + g * 8;
        bf16x8 bh0 = *reinterpret_cast<const bf16x8*>(wh);
        bf16x8 bh1 = *reinterpret_cast<const bf16x8*>(wh + 32);
        bf16x8 bl0 = *reinterpret_cast<const bf16x8*>(wl);
        bf16x8 bl1 = *reinterpret_cast<const bf16x8*>(wl + 32);
        const float wq = wsq[c];

        #pragma unroll
        for (int s = 0; s < 4; ++s) {
            f32x4 acc = {0.f, 0.f, 0.f, 0.f};
            acc = __builtin_amdgcn_mfma_f32_16x16x32_bf16(xh[s][0], bh0, acc, 0, 0, 0);
            acc = __builtin_amdgcn_mfma_f32_16x16x32_bf16(xh[s][1], bh1, acc, 0, 0, 0);
            acc = __builtin_amdgcn_mfma_f32_16x16x32_bf16(xl[s][0], bh0, acc, 0, 0, 0);
            acc = __builtin_amdgcn_mfma_f32_16x16x32_bf16(xl[s][1], bh1, acc, 0, 0, 0);
            acc = __builtin_amdgcn_mfma_f32_16x16x32_bf16(xh[s][0], bl0, acc, 0, 0, 0);
            acc = __builtin_amdgcn_mfma_f32_16x16x32_bf16(xh[s][1], bl1, acc, 0, 0, 0);
            #pragma unroll
            for (int i = 0; i < 4; ++i) {
                float d = __fmaf_rn(-2.0f, acc[i], wq);      // fsq cancels in argmin
                float o1 = d1[s][i];
                d2[s][i] = fminf(d2[s][i], fmaxf(d, o1));    // streaming 2nd-min
                bool lt = d < o1;
                d1[s][i] = lt ? d : o1;
                i1[s][i] = lt ? c : i1[s][i];
            }
        }
    }

    // ---- per-row merge across the 16 code-lanes of each group -> LDS ----
    #pragma unroll
    for (int s = 0; s < 4; ++s)
        #pragma unroll
        for (int i = 0; i < 4; ++i) {
            float a1 = d1[s][i], a2 = d2[s][i]; int ai = i1[s][i];
            #pragma unroll
            for (int m = 1; m < 16; m <<= 1) {   // xor<16 stays inside 16-lane group
                float o1 = __shfl_xor(a1, m, 64);
                float o2 = __shfl_xor(a2, m, 64);
                int   oi = __shfl_xor(ai, m, 64);
                float n1 = fminf(a1, o1);
                a2 = fminf(fminf(a2, o2), fmaxf(a1, o1));
                ai = (o1 < a1) ? oi : ai;
                a1 = n1;
            }
            if (c16 == 0) {
                int r = s * 16 + g * 4 + i;      // row within block
                sD1[wv][r] = a1; sD2[wv][r] = a2; sI1[wv][r] = ai;
            }
        }
    __syncthreads();

    // ---- cross-wave top-2 fold (ascending wave order = ascending code blocks) ----
    if (tid < 64) {
        int row = rbase + tid;
        float m1 = sD1[0][tid], m2 = sD2[0][tid]; int mi = sI1[0][tid];
        #pragma unroll
        for (int w = 1; w < 4; ++w) {
            float a = sD1[w][tid], b = sD2[w][tid]; int ii = sI1[w][tid];
            if (a < m1) { m2 = fminf(m1, b); mi = ii; m1 = a; }
            else        { m2 = fminf(m2, a); }       // tie -> gap 0 -> flagged
        }
        if (row < N) {
            idx_final[row] = mi;
            if (m2 - m1 <= VQ_MARGIN) {
                unsigned int pos = atomicAdd(ctr, 1u);
                if (pos < (unsigned)N) flags[pos] = row;
            }
        }
    }
}

// ================= Pass B: exact fp32 recheck, one BLOCK per flagged row ========
// 4 waves split K 4-ways; per lane 4 codes, 64 independent float4 loads (deep
// vmcnt pipeline). Formula bit-identical to the proven round-2/4 path.
__global__ __launch_bounds__(256) void vq_recheck_kernel(
    const float* __restrict__ x, const float* __restrict__ W,
    const float* __restrict__ wsq, const int* __restrict__ flags,
    const unsigned int* __restrict__ ctr, int* __restrict__ idx_final, int N, int K)
{
    __shared__ float sBD[4];
    __shared__ int   sBI[4];

    const int tid  = threadIdx.x;
    const int wv   = tid >> 6;
    const int lane = tid & 63;
    unsigned int cnt = *ctr;
    if (cnt > (unsigned)N) cnt = (unsigned)N;

    const float4* W4 = reinterpret_cast<const float4*>(W);
    for (unsigned int t = blockIdx.x; t < cnt; t += gridDim.x) {
        const int row = flags[t];
        float f[VQ_D];
        {
            const float4* xf = reinterpret_cast<const float4*>(x) + (size_t)row * (VQ_D / 4);
            #pragma unroll
            for (int i = 0; i < VQ_D / 4; ++i) {   // uniform-address broadcast loads
                float4 v = xf[i];
                f[4 * i + 0] = v.x; f[4 * i + 1] = v.y;
                f[4 * i + 2] = v.z; f[4 * i + 3] = v.w;
            }
        }
        float s0 = 0.f, s1 = 0.f, s2 = 0.f, s3 = 0.f;
        #pragma unroll
        for (int q = 0; q < VQ_D; q += 4) {
            s0 = __fmaf_rn(f[q], f[q], s0);         s1 = __fmaf_rn(f[q + 1], f[q + 1], s1);
            s2 = __fmaf_rn(f[q + 2], f[q + 2], s2); s3 = __fmaf_rn(f[q + 3], f[q + 3], s3);
        }
        const float fsq = (s0 + s1) + (s2 + s3);

        float best = 3.4e38f; int bidx = 0x7fffffff;
        #pragma unroll
        for (int tt = 0; tt < 4; ++tt) {            // wave slice: c ascending per lane
            const int c = wv * (K >> 2) + tt * 64 + lane;
            const float4* wc = W4 + (size_t)c * (VQ_D / 4);
            float d0 = 0.f, dd1 = 0.f, dd2 = 0.f, dd3 = 0.f;
            #pragma unroll
            for (int i = 0; i < VQ_D / 4; ++i) {
                float4 w = wc[i];
                d0  = __fmaf_rn(f[4 * i + 0], w.x, d0);
                dd1 = __fmaf_rn(f[4 * i + 1], w.y, dd1);
                dd2 = __fmaf_rn(f[4 * i + 2], w.z, dd2);
                dd3 = __fmaf_rn(f[4 * i + 3], w.w, dd3);
            }
            float dot  = (d0 + dd1) + (dd2 + dd3);
            float dist = __fmaf_rn(-2.0f, dot, fsq + wsq[c]);
            if (dist < best || (dist == best && c < bidx)) { best = dist; bidx = c; }
        }
        #pragma unroll
        for (int m = 1; m < 64; m <<= 1) {          // lexicographic (dist, idx) min
            float od = __shfl_xor(best, m, 64);
            int   oi = __shfl_xor(bidx, m, 64);
            if (od < best || (od == best && oi < bidx)) { best = od; bidx = oi; }
        }
        if (lane == 0) { sBD[wv] = best; sBI[wv] = bidx; }
        __syncthreads();
        if (tid == 0) {
            float m1 = sBD[0]; int mi = sBI[0];
            #pragma unroll
            for (int w = 1; w < 4; ++w) {
                float a = sBD[w]; int ii = sBI[w];
                if (a < m1 || (a == m1 && ii < mi)) { m1 = a; mi = ii; }
            }
            idx_final[row] = mi;
        }
        __syncthreads();                             // protect sBD/sBI for next row
    }
}

// ================= Pass C: gather + outputs (round-4 proven epilogue) ===========
__global__ __launch_bounds__(256) void vq_gather_kernel(
    const float* __restrict__ x, const float* __restrict__ W,
    const int* __restrict__ idx_final, float* __restrict__ out, int N)
{
    __shared__ int sIdx[64];
    const int tid = threadIdx.x;
    const int rbase = blockIdx.x * 64;
    if (tid < 64 && rbase + tid < N) {
        int idx = idx_final[rbase + tid];
        sIdx[tid] = idx;
        out[(size_t)2 * N * VQ_D + rbase + tid] = (float)idx;   // coalesced
    }
    __syncthreads();
    const float4* W4 = reinterpret_cast<const float4*>(W);
    const float4* X4 = reinterpret_cast<const float4*>(x);
    float4* O0 = reinterpret_cast<float4*>(out);
    float4* O1 = O0 + (size_t)N * (VQ_D / 4);
    const size_t base4 = (size_t)rbase * (VQ_D / 4);
    #pragma unroll
    for (int i = 0; i < 4; ++i) {
        int j = i * 256 + tid;               // 0..1023, lane-consecutive
        int rowo = j >> 4;                   // 16 lanes share a row
        int d4 = j & 15;
        if (rbase + rowo < N) {
            int idx = sIdx[rowo];
            float4 w = W4[(size_t)idx * (VQ_D / 4) + d4];   // 256B contiguous, L2-hot
            float4 xv = X4[base4 + j];
            float4 o;                         // out0 = x + (q - x): ref double-rounding
            o.x = xv.x + (w.x - xv.x);
            o.y = xv.y + (w.y - xv.y);
            o.z = xv.z + (w.z - xv.z);
            o.w = xv.w + (w.w - xv.w);
            O0[base4 + j] = o;
            O1[base4 + j] = w;
        }
    }
}

// ================= Fallback: proven round-4 pipeline ===========================
__global__ __launch_bounds__(256) void vq_wsq_kernel(const float* __restrict__ W,
                                                     float* __restrict__ wsq, int K)
{
    int c = blockIdx.x * 256 + threadIdx.x;
    if (c >= K) return;
    const float4* w4 = reinterpret_cast<const float4*>(W) + (size_t)c * (VQ_D / 4);
    float s0 = 0.f, s1 = 0.f, s2 = 0.f, s3 = 0.f;
    #pragma unroll
    for (int j = 0; j < VQ_D / 4; ++j) {
        float4 v = w4[j];
        s0 = __fmaf_rn(v.x, v.x, s0); s1 = __fmaf_rn(v.y, v.y, s1);
        s2 = __fmaf_rn(v.z, v.z, s2); s3 = __fmaf_rn(v.w, v.w, s3);
    }
    wsq[c] = (s0 + s1) + (s2 + s3);
}

__global__ __launch_bounds__(256, 6) void vq_main_kernel(const float* __restrict__ x,
    const float* __restrict__ W, const float* __restrict__ wsq,
    float* __restrict__ out, int N, int K)
{
    __shared__ unsigned long long sMerge[256];
    __shared__ int sIdx[64];
    const int tid  = threadIdx.x;
    const int lane = tid & 63;
    const int rbase = blockIdx.x * 64;
    const int row  = rbase + lane;
    const int lrow = (row < N) ? row : (N - 1);
    float f[VQ_D];
    {
        const float4* xf = reinterpret_cast<const float4*>(x) + (size_t)lrow * (VQ_D / 4);
        #pragma unroll
        for (int i = 0; i < VQ_D / 4; ++i) {
            float4 v = xf[i];
            f[4 * i + 0] = v.x; f[4 * i + 1] = v.y;
            f[4 * i + 2] = v.z; f[4 * i + 3] = v.w;
        }
    }
    float fsq;
    {
        float s0 = 0.f, s1 = 0.f, s2 = 0.f, s3 = 0.f;
        #pragma unroll
        for (int q = 0; q < VQ_D; q += 4) {
            s0 = __fmaf_rn(f[q], f[q], s0);         s1 = __fmaf_rn(f[q + 1], f[q + 1], s1);
            s2 = __fmaf_rn(f[q + 2], f[q + 2], s2); s3 = __fmaf_rn(f[q + 3], f[q + 3], s3);
        }
        fsq = (s0 + s1) + (s2 + s3);
    }
    const int slice = __builtin_amdgcn_readfirstlane(tid >> 6);
    const int c0 = slice * (K >> 2);
    const int c1 = c0 + (K >> 2);
    float best = 3.4e38f;
    int bidx = c0;
    const float4* __restrict__ W4 = reinterpret_cast<const float4*>(W);
    #pragma unroll 2
    for (int c = c0; c < c1; ++c) {
        const float4* wc = W4 + (size_t)c * (VQ_D / 4);
        float d0 = 0.f, d1 = 0.f, d2 = 0.f, d3 = 0.f;
        #pragma unroll
        for (int i = 0; i < VQ_D / 4; ++i) {
            float4 w = wc[i];
            d0 = __fmaf_rn(f[4 * i + 0], w.x, d0); d1 = __fmaf_rn(f[4 * i + 1], w.y, d1);
            d2 = __fmaf_rn(f[4 * i + 2], w.z, d2); d3 = __fmaf_rn(f[4 * i + 3], w.w, d3);
        }
        float dot = (d0 + d1) + (d2 + d3);
        float dist = __fmaf_rn(-2.0f, dot, fsq + wsq[c]);
        if (dist < best) { best = dist; bidx = c; }
    }
    best = fmaxf(best, 0.0f);
    sMerge[tid] = ((unsigned long long)__float_as_uint(best) << 32) | (unsigned int)bidx;
    __syncthreads();
    if (tid < 64) {
        unsigned long long mm = sMerge[tid];
        unsigned long long a = sMerge[tid + 64];  if (a < mm) mm = a;
        unsigned long long b = sMerge[tid + 128]; if (b < mm) mm = b;
        unsigned long long d = sMerge[tid + 192]; if (d < mm) mm = d;
        int idx = (int)(mm & 0xFFFFFFFFu);
        sIdx[tid] = idx;
        if (rbase + tid < N) out[(size_t)2 * N * VQ_D + rbase + tid] = (float)idx;
    }
    __syncthreads();
    const float4* X4 = reinterpret_cast<const float4*>(x);
    float4* O0 = reinterpret_cast<float4*>(out);
    float4* O1 = O0 + (size_t)N * (VQ_D / 4);
    const size_t base4 = (size_t)rbase * (VQ_D / 4);
    #pragma unroll
    for (int i = 0; i < 4; ++i) {
        int j = i * 256 + tid;
        int rowo = j >> 4, d4 = j & 15;
        if (rbase + rowo < N) {
            int idx = sIdx[rowo];
            float4 w = W4[(size_t)idx * (VQ_D / 4) + d4];
            float4 xv = X4[base4 + j];
            float4 o;
            o.x = xv.x + (w.x - xv.x); o.y = xv.y + (w.y - xv.y);
            o.z = xv.z + (w.z - xv.z); o.w = xv.w + (w.w - xv.w);
            O0[base4 + j] = o; O1[base4 + j] = w;
        }
    }
}

// ================= Launcher ====================================================
extern "C" void kernel_launch(void* const* d_in, const int* in_sizes, int n_in,
                              void* d_out, int out_size, void* d_ws, size_t ws_size,
                              hipStream_t stream)
{
    const float* x = (const float*)d_in[0];
    const float* W = (const float*)d_in[1];
    float* out = (float*)d_out;
    const int N = in_sizes[0] / VQ_D;   // 131072
    const int K = in_sizes[1] / VQ_D;   // 1024

    // ws layout
    char* ws = (char*)d_ws;
    float*          wsq  = (float*)ws;                            // 4 KB
    unsigned int*   ctr  = (unsigned int*)(ws + 4096);            // 4 B (+pad)
    int*            flags= (int*)(ws + 8192);                     // 4N
    int*            idxf = (int*)(ws + 8192 + (size_t)N * 4);     // 4N
    unsigned short* Whi  = (unsigned short*)(ws + 8192 + (size_t)N * 8);
    unsigned short* Wlo  = Whi + (size_t)K * VQ_D;
    const size_t need = 8192 + (size_t)N * 8 + (size_t)K * VQ_D * 4;

    if (ws_size >= need && (N % 64) == 0 && (K % 256) == 0) {
        vq_prep_kernel<<<(K + 255) / 256, 256, 0, stream>>>(W, Whi, Wlo, wsq, ctr, K);
        vq_mfma_kernel<<<N / 64, 256, 0, stream>>>(x, Whi, Wlo, wsq,
                                                   idxf, flags, ctr, N, K);
        vq_recheck_kernel<<<4096, 256, 0, stream>>>(x, W, wsq, flags, ctr, idxf, N, K);
        vq_gather_kernel<<<N / 64, 256, 0, stream>>>(x, W, idxf, out, N);
    } else {
        vq_wsq_kernel<<<(K + 255) / 256, 256, 0, stream>>>(W, wsq, K);
        vq_main_kernel<<<(N + 63) / 64, 256, 0, stream>>>(x, W, wsq, out, N, K);
    }
}

// Round 7
// 178.378 us; speedup vs baseline: 2.4860x; 1.1569x over previous
//
#include <hip/hip_runtime.h>

#define VQ_D 64
#define VQ_MARGIN 0.015f

typedef __attribute__((ext_vector_type(8))) short bf16x8;   // 8 bf16 = 4 VGPRs
typedef __attribute__((ext_vector_type(4))) float f32x4;

static __device__ __forceinline__ unsigned short bf16_rne(float v) {
    unsigned u = __float_as_uint(v);
    u += 0x7fffu + ((u >> 16) & 1u);
    return (unsigned short)(u >> 16);
}

// ================= Prep: pack W into MFMA-fragment order + wsq =================
// One thread per (tile ct, lane l). Emits:
//   Wpk[(ct*4+f)*64 + l] : 16B fragment lane l loads for frag f of tile ct
//     f=0: hi k=g*8..+8 | f=1: hi k=32+g*8 | f=2: lo k=g*8 | f=3: lo k=32+g*8
//     (c = ct*16 + (l&15), g = l>>6? no: g = l>>4)  -- bit-identical data to r6
//   wsqpk[ct*64 + l] = wsq[ct*16 + (l&15)]   (coalesced per-tile dword load)
//   wsq[c] exact fp32 (4-accumulator structure; recheck depends on it)
__global__ __launch_bounds__(256) void vq_prep_kernel(
    const float* __restrict__ W, unsigned short* __restrict__ Wpk,
    float* __restrict__ wsqpk, float* __restrict__ wsq,
    unsigned int* __restrict__ ctr, int K)
{
    const int t = blockIdx.x * 256 + threadIdx.x;
    if (t == 0) *ctr = 0u;
    const int NT = K >> 4;
    if (t >= NT * 64) return;
    const int ct = t >> 6;
    const int l  = t & 63;
    const int c  = ct * 16 + (l & 15);
    const int g  = l >> 4;

    const float* wr = W + (size_t)c * VQ_D;

    // exact wsq (round-2/4 proven structure)
    float s0 = 0.f, s1 = 0.f, s2 = 0.f, s3 = 0.f;
    const float4* w4 = reinterpret_cast<const float4*>(wr);
    #pragma unroll
    for (int j = 0; j < VQ_D / 4; ++j) {
        float4 v = w4[j];
        s0 = __fmaf_rn(v.x, v.x, s0); s1 = __fmaf_rn(v.y, v.y, s1);
        s2 = __fmaf_rn(v.z, v.z, s2); s3 = __fmaf_rn(v.w, v.w, s3);
    }
    const float wq = (s0 + s1) + (s2 + s3);
    wsqpk[ct * 64 + l] = wq;
    if (l < 16) wsq[ct * 16 + l] = wq;   // one writer per code

    // fragments (same hi/lo split as the passing r6 kernel)
    float v0[8], v1[8];
    {
        const float4* p0 = reinterpret_cast<const float4*>(wr + g * 8);
        const float4* p1 = reinterpret_cast<const float4*>(wr + 32 + g * 8);
        float4 a = p0[0], b = p0[1], cc = p1[0], d = p1[1];
        v0[0]=a.x; v0[1]=a.y; v0[2]=a.z; v0[3]=a.w; v0[4]=b.x; v0[5]=b.y; v0[6]=b.z; v0[7]=b.w;
        v1[0]=cc.x;v1[1]=cc.y;v1[2]=cc.z;v1[3]=cc.w;v1[4]=d.x; v1[5]=d.y; v1[6]=d.z; v1[7]=d.w;
    }
    bf16x8 h0, h1, l0, l1;
    #pragma unroll
    for (int j = 0; j < 8; ++j) {
        unsigned short hb0 = bf16_rne(v0[j]);
        unsigned short hb1 = bf16_rne(v1[j]);
        h0[j] = (short)hb0;
        h1[j] = (short)hb1;
        l0[j] = (short)bf16_rne(v0[j] - __uint_as_float((unsigned)hb0 << 16));
        l1[j] = (short)bf16_rne(v1[j] - __uint_as_float((unsigned)hb1 << 16));
    }
    bf16x8* P = reinterpret_cast<bf16x8*>(Wpk);
    P[(ct * 4 + 0) * 64 + l] = h0;
    P[(ct * 4 + 1) * 64 + l] = h1;
    P[(ct * 4 + 2) * 64 + l] = l0;
    P[(ct * 4 + 3) * 64 + l] = l1;
}

// ================= Pass A: MFMA argmin + margin flag + FUSED epilogue ==========
// Block = 4 waves, 64 rows; wave w scans tiles [w*NT/4, (w+1)*NT/4).
// All hot-loop global loads are fully coalesced (packed layout).
__global__ __launch_bounds__(256) void vq_mfma_kernel(
    const float* __restrict__ x, const float* __restrict__ W,
    const unsigned short* __restrict__ Wpk, const float* __restrict__ wsqpk,
    float* __restrict__ out, int* __restrict__ flags,
    unsigned int* __restrict__ ctr, int N, int K)
{
    __shared__ float sD1[4][64], sD2[4][64];
    __shared__ int   sI1[4][64];
    __shared__ int   sIdx[64];

    const int tid  = threadIdx.x;
    const int wv   = tid >> 6;        // wave 0..3
    const int lane = tid & 63;
    const int g    = lane >> 4;       // k-group 0..3
    const int c16  = lane & 15;
    const int rbase = blockIdx.x * 64;

    // ---- load 64 rows of x; split to bf16 hi/lo A-fragments (r6-verified) ----
    bf16x8 xh[4][2], xl[4][2];
    #pragma unroll
    for (int s = 0; s < 4; ++s) {
        int row = rbase + s * 16 + c16;
        if (row >= N) row = N - 1;
        const float* xr = x + (size_t)row * VQ_D;
        #pragma unroll
        for (int h = 0; h < 2; ++h) {
            const float4* p = reinterpret_cast<const float4*>(xr + h * 32 + g * 8);
            float4 v0 = p[0], v1 = p[1];
            float vv[8] = {v0.x, v0.y, v0.z, v0.w, v1.x, v1.y, v1.z, v1.w};
            #pragma unroll
            for (int j = 0; j < 8; ++j) {
                unsigned short hb = bf16_rne(vv[j]);
                float hf = __uint_as_float((unsigned)hb << 16);
                xh[s][h][j] = (short)hb;
                xl[s][h][j] = (short)bf16_rne(vv[j] - hf);
            }
        }
    }

    float d1[4][4], d2[4][4]; int i1[4][4];
    #pragma unroll
    for (int s = 0; s < 4; ++s)
        #pragma unroll
        for (int i = 0; i < 4; ++i) { d1[s][i] = 3.4e38f; d2[s][i] = 3.4e38f; i1[s][i] = 0; }

    const int NT = K >> 4;
    const int t0 = wv * (NT >> 2);
    const int t1 = t0 + (NT >> 2);
    const bf16x8* __restrict__ P = reinterpret_cast<const bf16x8*>(Wpk);

    #pragma unroll 2
    for (int ct = t0; ct < t1; ++ct) {
        const int c = ct * 16 + c16;                  // this lane's code column
        const int pb = ct * 256 + lane;               // packed fragment base
        bf16x8 bh0 = P[pb];                           // 1KB coalesced each
        bf16x8 bh1 = P[pb + 64];
        bf16x8 bl0 = P[pb + 128];
        bf16x8 bl1 = P[pb + 192];
        const float wq = wsqpk[ct * 64 + lane];       // 256B coalesced

        #pragma unroll
        for (int s = 0; s < 4; ++s) {
            f32x4 acc = {0.f, 0.f, 0.f, 0.f};
            acc = __builtin_amdgcn_mfma_f32_16x16x32_bf16(xh[s][0], bh0, acc, 0, 0, 0);
            acc = __builtin_amdgcn_mfma_f32_16x16x32_bf16(xh[s][1], bh1, acc, 0, 0, 0);
            acc = __builtin_amdgcn_mfma_f32_16x16x32_bf16(xl[s][0], bh0, acc, 0, 0, 0);
            acc = __builtin_amdgcn_mfma_f32_16x16x32_bf16(xl[s][1], bh1, acc, 0, 0, 0);
            acc = __builtin_amdgcn_mfma_f32_16x16x32_bf16(xh[s][0], bl0, acc, 0, 0, 0);
            acc = __builtin_amdgcn_mfma_f32_16x16x32_bf16(xh[s][1], bl1, acc, 0, 0, 0);
            #pragma unroll
            for (int i = 0; i < 4; ++i) {
                float d = __fmaf_rn(-2.0f, acc[i], wq);      // fsq cancels in argmin
                float o1 = d1[s][i];
                d2[s][i] = fminf(d2[s][i], fmaxf(d, o1));    // streaming 2nd-min
                bool lt = d < o1;
                d1[s][i] = lt ? d : o1;
                i1[s][i] = lt ? c : i1[s][i];
            }
        }
    }

    // ---- per-row merge across the 16 code-lanes of each group -> LDS ----
    #pragma unroll
    for (int s = 0; s < 4; ++s)
        #pragma unroll
        for (int i = 0; i < 4; ++i) {
            float a1 = d1[s][i], a2 = d2[s][i]; int ai = i1[s][i];
            #pragma unroll
            for (int m = 1; m < 16; m <<= 1) {   // xor<16 stays inside 16-lane group
                float o1 = __shfl_xor(a1, m, 64);
                float o2 = __shfl_xor(a2, m, 64);
                int   oi = __shfl_xor(ai, m, 64);
                float n1 = fminf(a1, o1);
                a2 = fminf(fminf(a2, o2), fmaxf(a1, o1));
                ai = (o1 < a1) ? oi : ai;
                a1 = n1;
            }
            if (c16 == 0) {
                int r = s * 16 + g * 4 + i;      // row within block
                sD1[wv][r] = a1; sD2[wv][r] = a2; sI1[wv][r] = ai;
            }
        }
    __syncthreads();

    // ---- cross-wave top-2 fold; tentative idx + near-tie flagging ----
    if (tid < 64) {
        int row = rbase + tid;
        float m1 = sD1[0][tid], m2 = sD2[0][tid]; int mi = sI1[0][tid];
        #pragma unroll
        for (int w = 1; w < 4; ++w) {
            float a = sD1[w][tid], b = sD2[w][tid]; int ii = sI1[w][tid];
            if (a < m1) { m2 = fminf(m1, b); mi = ii; m1 = a; }
            else        { m2 = fminf(m2, a); }       // tie -> gap 0 -> flagged
        }
        sIdx[tid] = mi;
        if (row < N) {
            out[(size_t)2 * N * VQ_D + row] = (float)mi;     // coalesced idx write
            if (m2 - m1 <= VQ_MARGIN) {
                unsigned int pos = atomicAdd(ctr, 1u);
                if (pos < (unsigned)N) flags[pos] = row;
            }
        }
    }
    __syncthreads();

    // ---- fused gather epilogue (round-4 proven pattern); flagged rows get
    //      overwritten by the recheck kernel afterwards ----
    const float4* W4 = reinterpret_cast<const float4*>(W);
    const float4* X4 = reinterpret_cast<const float4*>(x);
    float4* O0 = reinterpret_cast<float4*>(out);
    float4* O1 = O0 + (size_t)N * (VQ_D / 4);
    const size_t base4 = (size_t)rbase * (VQ_D / 4);
    #pragma unroll
    for (int i = 0; i < 4; ++i) {
        int j = i * 256 + tid;               // 0..1023, lane-consecutive
        int rowo = j >> 4;                   // 16 lanes share a row
        int d4 = j & 15;
        if (rbase + rowo < N) {
            int idx = sIdx[rowo];
            float4 w = W4[(size_t)idx * (VQ_D / 4) + d4];   // 256B contiguous, L2-hot
            float4 xv = X4[base4 + j];
            float4 o;                         // out0 = x + (q - x): ref double-rounding
            o.x = xv.x + (w.x - xv.x);
            o.y = xv.y + (w.y - xv.y);
            o.z = xv.z + (w.z - xv.z);
            o.w = xv.w + (w.w - xv.w);
            O0[base4 + j] = o;
            O1[base4 + j] = w;
        }
    }
}

// ================= Pass B: exact fp32 recheck + output fixup ===================
// One BLOCK per flagged row; 4 waves split K 4-ways. Formula bit-identical to
// the proven round-2/4 path. Writes the row's final idx AND both output rows.
__global__ __launch_bounds__(256) void vq_recheck_kernel(
    const float* __restrict__ x, const float* __restrict__ W,
    const float* __restrict__ wsq, const int* __restrict__ flags,
    const unsigned int* __restrict__ ctr, float* __restrict__ out, int N, int K)
{
    __shared__ float sBD[4];
    __shared__ int   sBI[4];
    __shared__ int   sFin;

    const int tid  = threadIdx.x;
    const int wv   = tid >> 6;
    const int lane = tid & 63;
    unsigned int cnt = *ctr;
    if (cnt > (unsigned)N) cnt = (unsigned)N;

    const float4* W4 = reinterpret_cast<const float4*>(W);
    for (unsigned int t = blockIdx.x; t < cnt; t += gridDim.x) {
        const int row = flags[t];
        float f[VQ_D];
        {
            const float4* xf = reinterpret_cast<const float4*>(x) + (size_t)row * (VQ_D / 4);
            #pragma unroll
            for (int i = 0; i < VQ_D / 4; ++i) {   // uniform-address broadcast loads
                float4 v = xf[i];
                f[4 * i + 0] = v.x; f[4 * i + 1] = v.y;
                f[4 * i + 2] = v.z; f[4 * i + 3] = v.w;
            }
        }
        float s0 = 0.f, s1 = 0.f, s2 = 0.f, s3 = 0.f;
        #pragma unroll
        for (int q = 0; q < VQ_D; q += 4) {
            s0 = __fmaf_rn(f[q], f[q], s0);         s1 = __fmaf_rn(f[q + 1], f[q + 1], s1);
            s2 = __fmaf_rn(f[q + 2], f[q + 2], s2); s3 = __fmaf_rn(f[q + 3], f[q + 3], s3);
        }
        const float fsq = (s0 + s1) + (s2 + s3);

        float best = 3.4e38f; int bidx = 0x7fffffff;
        #pragma unroll
        for (int tt = 0; tt < 4; ++tt) {            // wave slice: c ascending per lane
            const int c = wv * (K >> 2) + tt * 64 + lane;
            const float4* wc = W4 + (size_t)c * (VQ_D / 4);
            float d0 = 0.f, dd1 = 0.f, dd2 = 0.f, dd3 = 0.f;
            #pragma unroll
            for (int i = 0; i < VQ_D / 4; ++i) {
                float4 w = wc[i];
                d0  = __fmaf_rn(f[4 * i + 0], w.x, d0);
                dd1 = __fmaf_rn(f[4 * i + 1], w.y, dd1);
                dd2 = __fmaf_rn(f[4 * i + 2], w.z, dd2);
                dd3 = __fmaf_rn(f[4 * i + 3], w.w, dd3);
            }
            float dot  = (d0 + dd1) + (dd2 + dd3);
            float dist = __fmaf_rn(-2.0f, dot, fsq + wsq[c]);
            if (dist < best || (dist == best && c < bidx)) { best = dist; bidx = c; }
        }
        #pragma unroll
        for (int m = 1; m < 64; m <<= 1) {          // lexicographic (dist, idx) min
            float od = __shfl_xor(best, m, 64);
            int   oi = __shfl_xor(bidx, m, 64);
            if (od < best || (od == best && oi < bidx)) { best = od; bidx = oi; }
        }
        if (lane == 0) { sBD[wv] = best; sBI[wv] = bidx; }
        __syncthreads();
        if (tid == 0) {
            float m1 = sBD[0]; int mi = sBI[0];
            #pragma unroll
            for (int w = 1; w < 4; ++w) {
                float a = sBD[w]; int ii = sBI[w];
                if (a < m1 || (a == m1 && ii < mi)) { m1 = a; mi = ii; }
            }
            sFin = mi;
        }
        __syncthreads();
        const int mi = sFin;
        if (tid < 64) {                              // fix this row's outputs
            float wvv = W[(size_t)mi * VQ_D + tid];
            float xv  = x[(size_t)row * VQ_D + tid];
            out[(size_t)row * VQ_D + tid] = xv + (wvv - xv);
            out[(size_t)N * VQ_D + (size_t)row * VQ_D + tid] = wvv;
            if (tid == 0) out[(size_t)2 * N * VQ_D + row] = (float)mi;
        }
        __syncthreads();                             // protect shared for next row
    }
}

// ================= Fallback: proven round-4 pipeline ===========================
__global__ __launch_bounds__(256) void vq_wsq_kernel(const float* __restrict__ W,
                                                     float* __restrict__ wsq, int K)
{
    int c = blockIdx.x * 256 + threadIdx.x;
    if (c >= K) return;
    const float4* w4 = reinterpret_cast<const float4*>(W) + (size_t)c * (VQ_D / 4);
    float s0 = 0.f, s1 = 0.f, s2 = 0.f, s3 = 0.f;
    #pragma unroll
    for (int j = 0; j < VQ_D / 4; ++j) {
        float4 v = w4[j];
        s0 = __fmaf_rn(v.x, v.x, s0); s1 = __fmaf_rn(v.y, v.y, s1);
        s2 = __fmaf_rn(v.z, v.z, s2); s3 = __fmaf_rn(v.w, v.w, s3);
    }
    wsq[c] = (s0 + s1) + (s2 + s3);
}

__global__ __launch_bounds__(256, 6) void vq_main_kernel(const float* __restrict__ x,
    const float* __restrict__ W, const float* __restrict__ wsq,
    float* __restrict__ out, int N, int K)
{
    __shared__ unsigned long long sMerge[256];
    __shared__ int sIdx[64];
    const int tid  = threadIdx.x;
    const int lane = tid & 63;
    const int rbase = blockIdx.x * 64;
    const int row  = rbase + lane;
    const int lrow = (row < N) ? row : (N - 1);
    float f[VQ_D];
    {
        const float4* xf = reinterpret_cast<const float4*>(x) + (size_t)lrow * (VQ_D / 4);
        #pragma unroll
        for (int i = 0; i < VQ_D / 4; ++i) {
            float4 v = xf[i];
            f[4 * i + 0] = v.x; f[4 * i + 1] = v.y;
            f[4 * i + 2] = v.z; f[4 * i + 3] = v.w;
        }
    }
    float fsq;
    {
        float s0 = 0.f, s1 = 0.f, s2 = 0.f, s3 = 0.f;
        #pragma unroll
        for (int q = 0; q < VQ_D; q += 4) {
            s0 = __fmaf_rn(f[q], f[q], s0);         s1 = __fmaf_rn(f[q + 1], f[q + 1], s1);
            s2 = __fmaf_rn(f[q + 2], f[q + 2], s2); s3 = __fmaf_rn(f[q + 3], f[q + 3], s3);
        }
        fsq = (s0 + s1) + (s2 + s3);
    }
    const int slice = __builtin_amdgcn_readfirstlane(tid >> 6);
    const int c0 = slice * (K >> 2);
    const int c1 = c0 + (K >> 2);
    float best = 3.4e38f;
    int bidx = c0;
    const float4* __restrict__ W4 = reinterpret_cast<const float4*>(W);
    #pragma unroll 2
    for (int c = c0; c < c1; ++c) {
        const float4* wc = W4 + (size_t)c * (VQ_D / 4);
        float d0 = 0.f, d1 = 0.f, d2 = 0.f, d3 = 0.f;
        #pragma unroll
        for (int i = 0; i < VQ_D / 4; ++i) {
            float4 w = wc[i];
            d0 = __fmaf_rn(f[4 * i + 0], w.x, d0); d1 = __fmaf_rn(f[4 * i + 1], w.y, d1);
            d2 = __fmaf_rn(f[4 * i + 2], w.z, d2); d3 = __fmaf_rn(f[4 * i + 3], w.w, d3);
        }
        float dot = (d0 + d1) + (d2 + d3);
        float dist = __fmaf_rn(-2.0f, dot, fsq + wsq[c]);
        if (dist < best) { best = dist; bidx = c; }
    }
    best = fmaxf(best, 0.0f);
    sMerge[tid] = ((unsigned long long)__float_as_uint(best) << 32) | (unsigned int)bidx;
    __syncthreads();
    if (tid < 64) {
        unsigned long long mm = sMerge[tid];
        unsigned long long a = sMerge[tid + 64];  if (a < mm) mm = a;
        unsigned long long b = sMerge[tid + 128]; if (b < mm) mm = b;
        unsigned long long d = sMerge[tid + 192]; if (d < mm) mm = d;
        int idx = (int)(mm & 0xFFFFFFFFu);
        sIdx[tid] = idx;
        if (rbase + tid < N) out[(size_t)2 * N * VQ_D + rbase + tid] = (float)idx;
    }
    __syncthreads();
    const float4* X4 = reinterpret_cast<const float4*>(x);
    float4* O0 = reinterpret_cast<float4*>(out);
    float4* O1 = O0 + (size_t)N * (VQ_D / 4);
    const size_t base4 = (size_t)rbase * (VQ_D / 4);
    #pragma unroll
    for (int i = 0; i < 4; ++i) {
        int j = i * 256 + tid;
        int rowo = j >> 4, d4 = j & 15;
        if (rbase + rowo < N) {
            int idx = sIdx[rowo];
            float4 w = W4[(size_t)idx * (VQ_D / 4) + d4];
            float4 xv = X4[base4 + j];
            float4 o;
            o.x = xv.x + (w.x - xv.x); o.y = xv.y + (w.y - xv.y);
            o.z = xv.z + (w.z - xv.z); o.w = xv.w + (w.w - xv.w);
            O0[base4 + j] = o; O1[base4 + j] = w;
        }
    }
}

// ================= Launcher ====================================================
extern "C" void kernel_launch(void* const* d_in, const int* in_sizes, int n_in,
                              void* d_out, int out_size, void* d_ws, size_t ws_size,
                              hipStream_t stream)
{
    const float* x = (const float*)d_in[0];
    const float* W = (const float*)d_in[1];
    float* out = (float*)d_out;
    const int N = in_sizes[0] / VQ_D;   // 131072
    const int K = in_sizes[1] / VQ_D;   // 1024
    const int NT = K >> 4;              // 64 code-tiles

    // ws layout (16B-aligned segments)
    char* ws = (char*)d_ws;
    float*          wsq   = (float*)ws;                               // [0, 4K)
    unsigned int*   ctr   = (unsigned int*)(ws + 4096);               // 4 B
    int*            flags = (int*)(ws + 8192);                        // 4N
    unsigned short* Wpk   = (unsigned short*)(ws + 8192 + (size_t)N * 4);   // K*D*4 B
    float*          wsqpk = (float*)((char*)Wpk + (size_t)K * VQ_D * 4);    // NT*64*4 B
    const size_t need = 8192 + (size_t)N * 4 + (size_t)K * VQ_D * 4
                      + (size_t)NT * 64 * 4;

    if (ws_size >= need && (N % 64) == 0 && (K % 256) == 0) {
        vq_prep_kernel<<<(NT * 64 + 255) / 256, 256, 0, stream>>>(W, Wpk, wsqpk,
                                                                  wsq, ctr, K);
        vq_mfma_kernel<<<N / 64, 256, 0, stream>>>(x, W, Wpk, wsqpk,
                                                   out, flags, ctr, N, K);
        vq_recheck_kernel<<<2048, 256, 0, stream>>>(x, W, wsq, flags, ctr, out, N, K);
    } else {
        vq_wsq_kernel<<<(K + 255) / 256, 256, 0, stream>>>(W, wsq, K);
        vq_main_kernel<<<(N + 63) / 64, 256, 0, stream>>>(x, W, wsq, out, N, K);
    }
}